// Round 6
// baseline (798.402 us; speedup 1.0000x reference)
//
#include <hip/hip_runtime.h>

#define H 512
#define MTILE 64
#define NBLK 8192
#define HPAD 520
#define STEPC (2.4f / 63.0f)

typedef _Float16 half8 __attribute__((ext_vector_type(8)));
typedef float floatx4 __attribute__((ext_vector_type(4)));

__device__ inline float silu_f(float x) {
    return __fdividef(x, 1.0f + __expf(-x));
}

// ---- prep 1: lat_part[b][j] = b0[j] + sum_d lat[b][d] * W0[d][j] ----
__global__ void prep_latw(const float* __restrict__ lat, const float* __restrict__ W0,
                          const float* __restrict__ b0, float* __restrict__ latw) {
    __shared__ float sl[H];
    const int b = blockIdx.x;
    const int j = threadIdx.x;
    sl[j] = lat[b * H + j];
    __syncthreads();
    float acc = b0[j];
#pragma unroll 8
    for (int d = 0; d < H; ++d) acc += sl[d] * W0[d * H + j];
    latw[b * H + j] = acc;
}

// ---- prep 2: W1/W2 -> fp16, LANE-MAJOR fragment layout ----
// kc=k>>5, q=(k>>3)&3, k0=k&7; n -> nt=n>>7, w=(n>>4)&7, t=n&15.
// idx = (l*16+kc)*16384 + ((w*64 + q*16 + t)*4 + nt)*8 + k0
// => each lane's 4 nt-fragments are contiguous 64 B: one base pointer,
//    imm offsets 0/16/32/48 B, pointer advances 32 KB per kc. Zero per-load
//    vector address arithmetic in the K-loop.
__global__ void prep_w16(const float* __restrict__ W1, const float* __restrict__ W2,
                         _Float16* __restrict__ ws) {
    const int id = blockIdx.x * 512 + threadIdx.x;   // 0 .. 524287
    const int l = id >> 18;
    const int rem = id & 0x3FFFF;                    // k*512 + n
    const int k = rem >> 9, n = rem & 511;
    const float w = (l == 0 ? W1 : W2)[rem];
    const int kc = k >> 5, q = (k >> 3) & 3, k0 = k & 7;
    const int nt = n >> 7, wv = (n >> 4) & 7, t = n & 15;
    ws[(size_t)(l * 16 + kc) * 16384 + ((wv * 64 + q * 16 + t) * 4 + nt) * 8 + k0] = (_Float16)w;
}

// ---- main fused kernel: barrier-free K-loop, B from L2, 2 blocks/CU ----
__global__ __launch_bounds__(512, 4) void mesh_main(
    const float* __restrict__ W0, const float* __restrict__ b1,
    const float* __restrict__ b2, const float* __restrict__ W3,
    const float* __restrict__ b3, const float* __restrict__ latw,
    const _Float16* __restrict__ wsB, float* __restrict__ out) {

    __shared__ _Float16 hbuf[MTILE][HPAD];        // 66.5 KB
    __shared__ float partials[8][MTILE];          // 2 KB

    const int tid = threadIdx.x;
    const int wave = tid >> 6, lane = tid & 63;
    const int q = lane >> 4, t = lane & 15;
    const int bi = blockIdx.x;
    const int b = bi >> 12;
    const int p0 = (bi & 4095) << 6;              // 64 rows (fixed x,y; m = z)
    const float c0 = -1.2f + (float)(p0 >> 12) * STEPC;
    const float c1 = -1.2f + (float)((p0 >> 6) & 63) * STEPC;

    // ---- layer 0: h0 = silu(lat_part + coords@W0c + b0) ----
    // thread owns 8 consecutive cols (jg) x 8 rows (mb): b128 LDS stores.
    {
        const int jg = (tid & 63) * 8;
        const int mb = (tid >> 6) * 8;
        float lw8[8], w28[8];
#pragma unroll
        for (int c = 0; c < 8; ++c) {
            const int j = jg + c;
            lw8[c] = latw[b * H + j]
                   + c0 * W0[(H + 0) * H + j]
                   + c1 * W0[(H + 1) * H + j];
            w28[c] = W0[(H + 2) * H + j];
        }
#pragma unroll
        for (int r = 0; r < 8; ++r) {
            const int m = mb + r;
            const float c2v = -1.2f + (float)m * STEPC;
            half8 hv;
#pragma unroll
            for (int c = 0; c < 8; ++c)
                hv[c] = (_Float16)silu_f(lw8[c] + c2v * w28[c]);
            *(half8*)&hbuf[m][jg] = hv;
        }
    }

    // per-lane base into the lane-major B image
    const _Float16* wsl = wsB + (size_t)(wave * 64 + q * 16 + t) * 32;
    // per-lane base into hbuf for A fragments (row t, col q*8)
    const _Float16* arow0 = &hbuf[0][0] + t * HPAD + q * 8;

    floatx4 acc[4][4];

    auto zero_acc = [&]() {
#pragma unroll
        for (int mf = 0; mf < 4; ++mf)
#pragma unroll
            for (int nt = 0; nt < 4; ++nt) {
                acc[mf][nt][0] = 0.f; acc[mf][nt][1] = 0.f;
                acc[mf][nt][2] = 0.f; acc[mf][nt][3] = 0.f;
            }
    };

    auto loadB = [&](const _Float16* p, half8 (&bf)[4]) {
#pragma unroll
        for (int nt = 0; nt < 4; ++nt)
            bf[nt] = *(const half8*)(p + nt * 8);   // imm offsets 0/16/32/48 B
    };

    auto compute = [&](const _Float16* ar, half8 (&bf)[4]) {
        half8 a[4];
#pragma unroll
        for (int mf = 0; mf < 4; ++mf)
            a[mf] = *(const half8*)(ar + mf * 16 * HPAD);  // imm mf*16640 B
#pragma unroll
        for (int nt = 0; nt < 4; ++nt)
#pragma unroll
            for (int mf = 0; mf < 4; ++mf)
                acc[mf][nt] = __builtin_amdgcn_mfma_f32_16x16x32_f16(a[mf], bf[nt], acc[mf][nt], 0, 0, 0);
    };

    auto run_gemm = [&](int l) {
        const _Float16* p = wsl + (size_t)l * 16 * 16384;
        const _Float16* ar = arow0;
        half8 B0[4], B1[4];
        loadB(p, B0);
#pragma unroll 1
        for (int kc = 0; kc < 16; kc += 2) {
            loadB(p + 16384, B1);
            compute(ar, B0);
            loadB(p + 32768, B0);       // last iter reads guard slab: unused
            compute(ar + 32, B1);
            p += 32768;
            ar += 64;
        }
    };

    // ---- GEMM 1 ----
    zero_acc();
    __syncthreads();             // h0 ready
    run_gemm(0);
    __syncthreads();             // all waves done reading h0
    // writeback h1 = silu(acc + b1)
    {
        float b1v[4];
#pragma unroll
        for (int nt = 0; nt < 4; ++nt) b1v[nt] = b1[nt * 128 + wave * 16 + t];
#pragma unroll
        for (int mf = 0; mf < 4; ++mf)
#pragma unroll
            for (int nt = 0; nt < 4; ++nt)
#pragma unroll
                for (int r = 0; r < 4; ++r) {
                    const int m = mf * 16 + q * 4 + r;
                    const int col = nt * 128 + wave * 16 + t;
                    hbuf[m][col] = (_Float16)silu_f(acc[mf][nt][r] + b1v[nt]);
                }
    }

    // ---- GEMM 2 ----
    zero_acc();
    __syncthreads();             // h1 ready
    run_gemm(1);

    // ---- final layer: out = silu(acc + b2) @ W3 + b3 ----
    {
        float b2v[4], w3v[4];
#pragma unroll
        for (int nt = 0; nt < 4; ++nt) {
            const int col = nt * 128 + wave * 16 + t;
            b2v[nt] = b2[col];
            w3v[nt] = W3[col];
        }
#pragma unroll
        for (int mf = 0; mf < 4; ++mf)
#pragma unroll
            for (int r = 0; r < 4; ++r) {
                float sum = 0.f;
#pragma unroll
                for (int nt = 0; nt < 4; ++nt)
                    sum += silu_f(acc[mf][nt][r] + b2v[nt]) * w3v[nt];
                sum += __shfl_xor(sum, 1);
                sum += __shfl_xor(sum, 2);
                sum += __shfl_xor(sum, 4);
                sum += __shfl_xor(sum, 8);
                if (t == 0) partials[wave][mf * 16 + q * 4 + r] = sum;
            }
    }
    __syncthreads();
    if (tid < MTILE) {
        float o = b3[0];
#pragma unroll
        for (int w = 0; w < 8; ++w) o += partials[w][tid];
        out[(size_t)bi * MTILE + tid] = o;
    }
}

extern "C" void kernel_launch(void* const* d_in, const int* in_sizes, int n_in,
                              void* d_out, int out_size, void* d_ws, size_t ws_size,
                              hipStream_t stream) {
    const float* lat = (const float*)d_in[0];
    const float* W0  = (const float*)d_in[1];
    const float* b0  = (const float*)d_in[2];
    const float* W1  = (const float*)d_in[3];
    const float* b1  = (const float*)d_in[4];
    const float* W2  = (const float*)d_in[5];
    const float* b2  = (const float*)d_in[6];
    const float* W3  = (const float*)d_in[7];
    const float* b3  = (const float*)d_in[8];
    float* out = (float*)d_out;

    float* latw = (float*)d_ws;                               // 4 KB
    _Float16* wsB = (_Float16*)((char*)d_ws + 4096);          // 1 MB + 32 KB guard

    prep_latw<<<2, 512, 0, stream>>>(lat, W0, b0, latw);
    prep_w16<<<1024, 512, 0, stream>>>(W1, W2, wsB);
    mesh_main<<<NBLK, 512, 0, stream>>>(W0, b1, b2, W3, b3, latw, wsB, out);
}